// Round 6
// baseline (150.954 us; speedup 1.0000x reference)
//
#include <hip/hip_runtime.h>
#include <hip/hip_bf16.h>

typedef __bf16 bf16x8 __attribute__((ext_vector_type(8)));
typedef float floatx4 __attribute__((ext_vector_type(4)));

#define BATCH 256
#define INDIM 512
#define ODIM 10
#define HTOT 18432
#define NMODEL 128
#define BTILE 64
#define BK 64
#define LSTR 72      // bf16 elems per LDS row (64 data + 8 pad)
#define MAXS 256     // largest model (neurons)

__device__ __forceinline__ unsigned cvt2(float a, float b) {
    __hip_bfloat162 t = __float22bfloat162_rn(float2{a, b});   // RNE, packed
    return *(unsigned*)&t;                                      // low=a, high=b
}

__device__ __forceinline__ float apply_act(float h, int aidx) {
    if (aidx == 0) return fmaxf(h, 0.f);
    if (aidx == 1) return 1.f - 2.f / (1.f + __expf(2.f * h));   // tanh, no-overflow form
    if (aidx == 2) return 1.f / (1.f + __expf(-h));              // sigmoid
    return h;                                                     // identity
}

// ONE kernel. Block = (model m, 64-batch chunk bb). grid = 128*4 = 512 = 2/CU.
// XCD swizzle: bid&7 = XCD (dispatch round-robin heuristic); all 4 bb-blocks of
// a model share an XCD -> its w rows hit that XCD's L2 after first touch.
// Model m: rep=m/8, idx=m%8, S=32*(idx+1) neurons starting at J0. The whole
// segment-sum is block-local: wave wv owns b-range bb*64+wv*16+[0,16), all S j.
__global__ __launch_bounds__(256, 2) void fused_mlp_kernel(
    const float* __restrict__ x, const float* __restrict__ hw,
    const float* __restrict__ hb, const float* __restrict__ ow,
    const float* __restrict__ ob, float* __restrict__ out)
{
    __shared__ __align__(16) unsigned short wls[MAXS * LSTR];  // 36 KB
    __shared__ __align__(16) unsigned short xls[BTILE * LSTR]; // 9 KB
    __shared__ float wt[ODIM * MAXS];                          // 10 KB, [o][j]
    __shared__ float bt[MAXS];                                 // 1 KB

    const int tid = threadIdx.x;
    const int bid = blockIdx.x;
    const int xcd = bid & 7;
    const int k8  = bid >> 3;              // 0..63
    const int m   = xcd * 16 + (k8 >> 2);  // 16 models per XCD (2 full reps: balanced)
    const int bb  = k8 & 3;
    const int rep = m >> 3, idx = m & 7;
    const int cnt = idx + 1;
    const int S   = cnt * 32;              // model neurons
    const int J0  = 32 * (rep * 36 + (idx * (idx + 1)) / 2);
    const int b0  = bb * BTILE;
    const int aidx = J0 / 4608;            // model never crosses an act boundary (4608=4 reps)
    const int lane = tid & 63, wv = tid >> 6;
    const int r = lane & 15, g = lane >> 4;
    const int nj = 2 * cnt;                // # of 16-j tiles (2..16)

    // prologue: out_w slice [10][S] + bias (first __syncthreads covers them)
    #pragma unroll
    for (int o = 0; o < ODIM; o++)
        wt[o * MAXS + tid] = (tid < S) ? ow[(size_t)o * HTOT + J0 + tid] : 0.f;
    bt[tid] = (tid < S) ? hb[J0 + tid] : 0.f;

    floatx4 acc[16];
    #pragma unroll
    for (int jt = 0; jt < 16; jt++) acc[jt] = (floatx4)0.f;

    const floatx4* xv  = (const floatx4*)x;
    const floatx4* wv4 = (const floatx4*)hw;

    for (int kk = 0; kk < INDIM; kk += BK) {
        const int kq = kk >> 2;
        // x tile: 64 b x 64 k (1024 float4, 4/thread), fp32 -> bf16 inline
        #pragma unroll
        for (int i2 = 0; i2 < 4; i2++) {
            int f = tid + i2 * 256;
            int row = f >> 4, c4 = f & 15;
            floatx4 v = xv[(size_t)(b0 + row) * (INDIM / 4) + kq + c4];
            *(uint2*)&xls[row * LSTR + c4 * 4] = make_uint2(cvt2(v[0], v[1]), cvt2(v[2], v[3]));
        }
        // w tile: S j x 64 k (S*16 float4, runtime bound 2..16 per thread)
        for (int i = tid; i < S * 16; i += 256) {
            int row = i >> 4, c4 = i & 15;
            floatx4 u = wv4[(size_t)(J0 + row) * (INDIM / 4) + kq + c4];
            *(uint2*)&wls[row * LSTR + c4 * 4] = make_uint2(cvt2(u[0], u[1]), cvt2(u[2], u[3]));
        }
        __syncthreads();
        #pragma unroll
        for (int s = 0; s < 2; s++) {
            bf16x8 bfr = *(const bf16x8*)&xls[(wv * 16 + r) * LSTR + s * 32 + g * 8];
            #pragma unroll
            for (int jt = 0; jt < 16; jt++) {
                if (jt < nj) {   // compile-time indices, runtime predicate: acc stays in regs
                    bf16x8 af = *(const bf16x8*)&wls[(jt * 16 + r) * LSTR + s * 32 + g * 8];
                    acc[jt] = __builtin_amdgcn_mfma_f32_16x16x32_bf16(af, bfr, acc[jt], 0, 0, 0);
                }
            }
        }
        __syncthreads();
    }

    // Epilogue. D layout: col(b)=lane&15, row(j in 16-tile)=g*4+reg (verified R3-R5).
    // bias + activation in place, then dot with out_w and reduce over g-groups.
    #pragma unroll
    for (int jt = 0; jt < 16; jt++) {
        if (jt < nj) {
            #pragma unroll
            for (int q = 0; q < 4; q++)
                acc[jt][q] = apply_act(acc[jt][q] + bt[jt * 16 + g * 4 + q], aidx);
        }
    }

    const int b = b0 + wv * 16 + r;
    float* outp = out + (size_t)b * (NMODEL * ODIM) + m * ODIM;
    #pragma unroll
    for (int o = 0; o < ODIM; o++) {
        float p = 0.f;
        #pragma unroll
        for (int jt = 0; jt < 16; jt++) {
            if (jt < nj) {
                const float* wr = &wt[o * MAXS + jt * 16 + g * 4];  // broadcast reads
                p += acc[jt][0] * wr[0] + acc[jt][1] * wr[1]
                   + acc[jt][2] * wr[2] + acc[jt][3] * wr[3];
            }
        }
        p += __shfl_xor(p, 16, 64);
        p += __shfl_xor(p, 32, 64);
        if (lane < 16)
            outp[o] = p + ob[m * ODIM + o];   // single owner, plain store
    }
}

extern "C" void kernel_launch(void* const* d_in, const int* in_sizes, int n_in,
                              void* d_out, int out_size, void* d_ws, size_t ws_size,
                              hipStream_t stream) {
    const float* x   = (const float*)d_in[0];
    const float* hw  = (const float*)d_in[1];
    const float* hb  = (const float*)d_in[2];
    const float* ow  = (const float*)d_in[3];
    const float* ob  = (const float*)d_in[4];
    float* out = (float*)d_out;

    fused_mlp_kernel<<<NMODEL * (BATCH / BTILE), 256, 0, stream>>>(x, hw, hb, ow, ob, out);
}